// Round 6
// baseline (631.253 us; speedup 1.0000x reference)
//
#include <hip/hip_runtime.h>
#include <hip/hip_fp16.h>

#define NN 50000
#define NE 200000
#define IND 512
#define HIDD 2000
#define LATD 128

#define M_PAD 50048    // 782 * 64
#define N1_PAD 2048    // HIDD padded (pad cols forced to exact 0)
#define HT_LD 136      // h_tile LDS leading dim (272 B: 16B-aligned rows, bank-spread)

typedef _Float16 f16x8 __attribute__((ext_vector_type(8)));
typedef _Float16 f16x4 __attribute__((ext_vector_type(4)));
typedef float f32x4 __attribute__((ext_vector_type(4)));

__device__ __forceinline__ void gload_lds16(const _Float16* g, _Float16* l) {
    __builtin_amdgcn_global_load_lds(
        (const __attribute__((address_space(1))) unsigned int*)g,
        (__attribute__((address_space(3))) unsigned int*)l,
        16, 0, 0);
}

// ---- in-degree (int): deg[col[e]] += 1 ----
__global__ void k_degree(const int* __restrict__ col, int* __restrict__ deg) {
    int e = blockIdx.x * 256 + threadIdx.x;
    if (e < NE) atomicAdd(&deg[col[e]], 1);
}

// ---- dis = rsqrt(deg + 1 self-loop) ----
__global__ void k_dis(const int* __restrict__ deg, float* __restrict__ dis) {
    int i = blockIdx.x * 256 + threadIdx.x;
    if (i < NN) dis[i] = rsqrtf((float)deg[i] + 1.0f);
}

// ---- exclusive prefix scan of deg -> row_ptr (single 1024-thread block) ----
__global__ void k_scan(const int* __restrict__ deg, int* __restrict__ row_ptr) {
    __shared__ int smem[1024];
    const int tid = threadIdx.x;
    int carry = 0;
    for (int chunk = 0; chunk < NN; chunk += 1024) {
        int i = chunk + tid;
        int v = (i < NN) ? deg[i] : 0;
        smem[tid] = v;
        __syncthreads();
        #pragma unroll
        for (int off = 1; off < 1024; off <<= 1) {
            int t = (tid >= off) ? smem[tid - off] : 0;
            __syncthreads();
            if (tid >= off) smem[tid] += t;
            __syncthreads();
        }
        if (i < NN) row_ptr[i] = carry + smem[tid] - v;   // exclusive
        int tot = smem[1023];
        __syncthreads();
        carry += tot;
    }
    if (tid == 0) row_ptr[NN] = carry;
}

// ---- fill CSR: csr_src[row_ptr[c] + cursor[c]++] = r ----
__global__ void k_fill(const int* __restrict__ ei, const int* __restrict__ row_ptr,
                       int* __restrict__ cursor, int* __restrict__ csr_src) {
    int e = blockIdx.x * 256 + threadIdx.x;
    if (e < NE) {
        int r = ei[e], c = ei[NE + e];
        int pos = atomicAdd(&cursor[c], 1);
        csr_src[row_ptr[c] + pos] = r;
    }
}

// ---- LDS-tiled transpose+convert: in f32 [R][C] -> out fp16, out[c*ldo + r] ----
__global__ void k_transpose_tiled(const float* __restrict__ in,
                                  _Float16* __restrict__ out, int R, int C, int ldo) {
    __shared__ float sm[32][33];
    int c0 = blockIdx.x * 32, r0 = blockIdx.y * 32;
    int tx = threadIdx.x & 31, ty = threadIdx.x >> 5;   // 32 x 8
    #pragma unroll
    for (int i = 0; i < 4; ++i) {
        int r = r0 + ty + i * 8, c = c0 + tx;
        sm[ty + i * 8][tx] = (r < R && c < C) ? in[(size_t)r * C + c] : 0.f;
    }
    __syncthreads();
    #pragma unroll
    for (int i = 0; i < 4; ++i) {
        int c = c0 + ty + i * 8, r = r0 + tx;
        if (c < C && r < R) out[(size_t)c * ldo + r] = (_Float16)sm[tx][ty + i * 8];
    }
}

// ---- W2 [2000][128] f32 -> W2C [16][4][128][32] fp16 (chunk-major, zero-padded) ----
__global__ void k_w2c(const float* __restrict__ W2, _Float16* __restrict__ W2C) {
    int idx = blockIdx.x * 256 + threadIdx.x;
    if (idx >= 16 * 4 * 128 * 32) return;
    int kk  = idx & 31;
    int lat = (idx >> 5) & 127;
    int ki  = (idx >> 12) & 3;
    int j   = idx >> 14;
    int hid = j * 128 + ki * 32 + kk;
    W2C[idx] = (hid < HIDD) ? (_Float16)W2[(size_t)hid * LATD + lat] : (_Float16)0.f;
}

// ---- x f32 -> xh fp16 (8 elems/thread) ----
__global__ void k_xcvt(const float* __restrict__ in, _Float16* __restrict__ out, int n8) {
    int i = blockIdx.x * 256 + threadIdx.x;
    if (i < n8) {
        float4 a = ((const float4*)in)[i * 2];
        float4 b = ((const float4*)in)[i * 2 + 1];
        f16x8 o;
        o[0] = (_Float16)a.x; o[1] = (_Float16)a.y; o[2] = (_Float16)a.z; o[3] = (_Float16)a.w;
        o[4] = (_Float16)b.x; o[5] = (_Float16)b.y; o[6] = (_Float16)b.z; o[7] = (_Float16)b.w;
        ((f16x8*)out)[i] = o;
    }
}

// ---- gather-aggregate x (fp16 src): Ah[dst] = fp16(dd*(sum dis[s]*xh[s] + dd*xh[dst])) ----
__global__ void k_gather_x(const _Float16* __restrict__ xh, const int* __restrict__ row_ptr,
                           const int* __restrict__ csr_src, const float* __restrict__ dis,
                           _Float16* __restrict__ Ah) {
    int dst = blockIdx.x * 4 + (threadIdx.x >> 6);
    if (dst >= NN) return;
    int lane = threadIdx.x & 63;
    float dd = dis[dst];
    f16x8 sv = *(const f16x8*)(xh + (size_t)dst * IND + lane * 8);
    float acc[8];
    #pragma unroll
    for (int i = 0; i < 8; ++i) acc[i] = dd * (float)sv[i];
    int beg = row_ptr[dst], end = row_ptr[dst + 1];
    for (int i = beg; i < end; ++i) {
        int s = csr_src[i];
        float ns = dis[s];
        f16x8 v = *(const f16x8*)(xh + (size_t)s * IND + lane * 8);
        #pragma unroll
        for (int q = 0; q < 8; ++q) acc[q] += ns * (float)v[q];
    }
    f16x8 o;
    #pragma unroll
    for (int i = 0; i < 8; ++i) o[i] = (_Float16)(dd * acc[i]);
    *(f16x8*)(Ah + (size_t)dst * IND + lane * 8) = o;
}

// ---- gather-aggregate t + bias + sigmoid -> out (f32) ----
__global__ void k_gather_t(const float* __restrict__ t, const int* __restrict__ row_ptr,
                           const int* __restrict__ csr_src, const float* __restrict__ dis,
                           const float* __restrict__ b2, float* __restrict__ out) {
    int dst = blockIdx.x * 4 + (threadIdx.x >> 6);
    if (dst >= NN) return;
    int lane = threadIdx.x & 63;
    float dd = dis[dst];
    float2 td = *(const float2*)(t + (size_t)dst * LATD + lane * 2);
    float accx = dd * td.x, accy = dd * td.y;
    int beg = row_ptr[dst], end = row_ptr[dst + 1];
    for (int i = beg; i < end; ++i) {
        int s = csr_src[i];
        float ns = dis[s];
        float2 ts = *(const float2*)(t + (size_t)s * LATD + lane * 2);
        accx += ns * ts.x; accy += ns * ts.y;
    }
    float2 bb = *(const float2*)(b2 + lane * 2);
    float vx = dd * accx + bb.x;
    float vy = dd * accy + bb.y;
    float2 o;
    o.x = 1.0f / (1.0f + __expf(-vx));
    o.y = 1.0f / (1.0f + __expf(-vy));
    *(float2*)(out + (size_t)dst * LATD + lane * 2) = o;
}

// ---- FUSED: per 64-row block, for each 128-col chunk j of h:
//   stage1: hc = relu(Ah[64x512] @ W1C[j][128x512]^T + b1)   (swapped roles)
//   stage2: t_acc[128lat x 64m] += W2C[j] @ hc^T              (swapped roles)
// h never touches global memory.
__global__ __launch_bounds__(256, 2) void k_fused(
    const _Float16* __restrict__ Ah,   // [M_PAD][512]
    const _Float16* __restrict__ W1C,  // [2048][512] (pad rows zero)
    const float* __restrict__ b1p,     // [2048] (pad zeros)
    const _Float16* __restrict__ W2C,  // [16][4][128][32]
    float* __restrict__ t)             // [M_PAD][128]
{
    __shared__ __align__(16) _Float16 As[2 * 64 * 32];    //  8 KB: [slice][64 m][32 k]
    __shared__ __align__(16) _Float16 Bs[2 * 128 * 32];   // 16 KB: [slice][128 hc][32 k]
    __shared__ __align__(16) _Float16 W2s[4 * 128 * 32];  // 32 KB: [ki][128 lat][32 k]
    __shared__ __align__(16) _Float16 ht[64 * HT_LD];     // 17 KB: [64 m][128 hc] ld=136

    const int tid = threadIdx.x;
    const int lane = tid & 63;
    const int w = tid >> 6;
    const int mBase = blockIdx.x * 64;
    const int lm = lane & 15;
    const int quad = lane >> 4;

    // wave quadrants (same split both stages)
    const int wA = (w >> 1) * 64;   // stage1: W1-row block (h-col); stage2: lat block
    const int wB = (w & 1) * 32;    // stage1: Ah-row block (m);    stage2: m block

    // staging sources (per-lane) and LDS dests (wave-uniform; HW adds lane*16B)
    const _Float16* AgBase = Ah + (size_t)(mBase + w * 16 + (lane >> 2)) * IND + (lane & 3) * 8;
    const _Float16* BgBase = W1C + (size_t)(w * 32 + (lane >> 2)) * IND + (lane & 3) * 8;
    const _Float16* W2gBase = W2C + w * 4096 + lane * 8;
    _Float16* AsD  = As + w * 512;
    _Float16* BsD  = Bs + w * 1024;
    _Float16* W2sD = W2s + w * 4096;

    f32x4 acc2[4][2];
    #pragma unroll
    for (int i = 0; i < 4; ++i)
        #pragma unroll
        for (int j = 0; j < 2; ++j)
            acc2[i][j] = (f32x4){0.f, 0.f, 0.f, 0.f};

    for (int j = 0; j < 16; ++j) {
        // W2 chunk staging (contiguous; drains by first sync, read after epilogue sync)
        #pragma unroll
        for (int i = 0; i < 8; ++i)
            gload_lds16(W2gBase + (size_t)j * 16384 + i * 512, W2sD + i * 512);

        f32x4 acc1[4][2];
        #pragma unroll
        for (int mi = 0; mi < 4; ++mi)
            #pragma unroll
            for (int ni = 0; ni < 2; ++ni)
                acc1[mi][ni] = (f32x4){0.f, 0.f, 0.f, 0.f};

        // ---- stage 1 K-loop: BK=64 (2 slices of 32) ----
        for (int k0 = 0; k0 < IND; k0 += 64) {
            #pragma unroll
            for (int s = 0; s < 2; ++s) {
                gload_lds16(AgBase + k0 + s * 32, AsD + s * 2048);
                #pragma unroll
                for (int g = 0; g < 2; ++g)
                    gload_lds16(BgBase + (size_t)(j * 128 + g * 16) * IND + k0 + s * 32,
                                BsD + s * 4096 + g * 512);
            }
            __syncthreads();
            #pragma unroll
            for (int s = 0; s < 2; ++s) {
                f16x8 wf[4], af[2];
                #pragma unroll
                for (int mi = 0; mi < 4; ++mi)
                    wf[mi] = *(const f16x8*)&Bs[s * 4096 + (wA + mi * 16 + lm) * 32 + quad * 8];
                #pragma unroll
                for (int ni = 0; ni < 2; ++ni)
                    af[ni] = *(const f16x8*)&As[s * 2048 + (wB + ni * 16 + lm) * 32 + quad * 8];
                #pragma unroll
                for (int mi = 0; mi < 4; ++mi)
                    #pragma unroll
                    for (int ni = 0; ni < 2; ++ni)
                        acc1[mi][ni] = __builtin_amdgcn_mfma_f32_16x16x32_f16(
                            wf[mi], af[ni], acc1[mi][ni], 0, 0, 0);
            }
            __syncthreads();
        }

        // ---- epilogue: bias + relu + fp16, pack 4 consecutive h-cols -> ds_write_b64 ----
        // D1 layout: h-col = wA + mi*16 + quad*4 + r ; h-row(m) = wB + ni*16 + lm
        #pragma unroll
        for (int mi = 0; mi < 4; ++mi) {
            int hc0 = wA + mi * 16 + quad * 4;
            float4 b4 = *(const float4*)&b1p[j * 128 + hc0];
            #pragma unroll
            for (int ni = 0; ni < 2; ++ni) {
                int hrow = wB + ni * 16 + lm;
                f16x4 pk;
                pk[0] = (_Float16)fmaxf(acc1[mi][ni][0] + b4.x, 0.f);
                pk[1] = (_Float16)fmaxf(acc1[mi][ni][1] + b4.y, 0.f);
                pk[2] = (_Float16)fmaxf(acc1[mi][ni][2] + b4.z, 0.f);
                pk[3] = (_Float16)fmaxf(acc1[mi][ni][3] + b4.w, 0.f);
                *(f16x4*)&ht[hrow * HT_LD + hc0] = pk;
            }
        }
        __syncthreads();   // ht + W2s visible

        // ---- stage 2: t_acc[lat][m] += W2C[j] (A-role) x ht (B-role) ----
        #pragma unroll
        for (int ki = 0; ki < 4; ++ki) {
            f16x8 w2f[4], hf[2];
            #pragma unroll
            for (int mi = 0; mi < 4; ++mi)
                w2f[mi] = *(const f16x8*)&W2s[ki * 4096 + (wA + mi * 16 + lm) * 32 + quad * 8];
            #pragma unroll
            for (int ni = 0; ni < 2; ++ni)
                hf[ni] = *(const f16x8*)&ht[(wB + ni * 16 + lm) * HT_LD + ki * 32 + quad * 8];
            #pragma unroll
            for (int mi = 0; mi < 4; ++mi)
                #pragma unroll
                for (int ni = 0; ni < 2; ++ni)
                    acc2[mi][ni] = __builtin_amdgcn_mfma_f32_16x16x32_f16(
                        w2f[mi], hf[ni], acc2[mi][ni], 0, 0, 0);
        }
        __syncthreads();   // protect ht/W2s/As/Bs before next chunk
    }

    // ---- final t store: D2 layout: lat = wA + mi*16 + quad*4 + r ; m = wB + ni*16 + lm ----
    #pragma unroll
    for (int mi = 0; mi < 4; ++mi) {
        int lat0 = wA + mi * 16 + quad * 4;
        #pragma unroll
        for (int ni = 0; ni < 2; ++ni) {
            int m = mBase + wB + ni * 16 + lm;
            *(f32x4*)&t[(size_t)m * LATD + lat0] = acc2[mi][ni];
        }
    }
}

extern "C" void kernel_launch(void* const* d_in, const int* in_sizes, int n_in,
                              void* d_out, int out_size, void* d_ws, size_t ws_size,
                              hipStream_t stream) {
    const float* x  = (const float*)d_in[0];
    const int* ei   = (const int*)d_in[1];
    const float* W1 = (const float*)d_in[2];
    const float* b1 = (const float*)d_in[3];
    const float* W2 = (const float*)d_in[4];
    const float* b2 = (const float*)d_in[5];
    float* out = (float*)d_out;

    char* p = (char*)d_ws;
    auto alloc = [&](size_t bytes) {
        char* q = p; p += (bytes + 255) & ~(size_t)255; return q;
    };
    int* deg        = (int*)alloc((size_t)NN * 4);
    int* row_ptr    = (int*)alloc((size_t)(NN + 1) * 4);
    int* cursor     = (int*)alloc((size_t)NN * 4);
    int* csr_src    = (int*)alloc((size_t)NE * 4);
    float* dis      = (float*)alloc((size_t)NN * 4);
    float* b1pad    = (float*)alloc((size_t)N1_PAD * 4);
    _Float16* W1C   = (_Float16*)alloc((size_t)N1_PAD * IND * 2);   // [2048][512]
    _Float16* W2Cb  = (_Float16*)alloc((size_t)16 * 4 * 128 * 32 * 2);
    _Float16* xh    = (_Float16*)alloc((size_t)NN * IND * 2);
    _Float16* Ah    = (_Float16*)alloc((size_t)M_PAD * IND * 2);
    float* t        = (float*)alloc((size_t)M_PAD * LATD * 4);

    hipMemsetAsync(deg,    0, (size_t)NN * 4, stream);
    hipMemsetAsync(cursor, 0, (size_t)NN * 4, stream);
    hipMemsetAsync(b1pad,  0, (size_t)N1_PAD * 4, stream);
    hipMemsetAsync(W1C,    0, (size_t)N1_PAD * IND * 2, stream);
    hipMemcpyAsync(b1pad, b1, (size_t)HIDD * 4, hipMemcpyDeviceToDevice, stream);

    k_degree<<<(NE + 255) / 256, 256, 0, stream>>>(ei + NE, deg);
    k_dis<<<(NN + 255) / 256, 256, 0, stream>>>(deg, dis);
    k_scan<<<1, 1024, 0, stream>>>(deg, row_ptr);
    k_fill<<<(NE + 255) / 256, 256, 0, stream>>>(ei, row_ptr, cursor, csr_src);

    {
        dim3 gt1((HIDD + 31) / 32, (IND + 31) / 32);
        k_transpose_tiled<<<gt1, 256, 0, stream>>>(W1, W1C, IND, HIDD, IND);
        k_w2c<<<(16 * 4 * 128 * 32 + 255) / 256, 256, 0, stream>>>(W2, W2Cb);
        k_xcvt<<<(NN * IND / 8 + 255) / 256, 256, 0, stream>>>(x, xh, NN * IND / 8);
    }

    k_gather_x<<<(NN + 3) / 4, 256, 0, stream>>>(xh, row_ptr, csr_src, dis, Ah);

    k_fused<<<M_PAD / 64, 256, 0, stream>>>(Ah, W1C, b1pad, W2Cb, t);

    k_gather_t<<<(NN + 3) / 4, 256, 0, stream>>>(t, row_ptr, csr_src, dis, b2, out);
}

// Round 7
// 506.302 us; speedup vs baseline: 1.2468x; 1.2468x over previous
//
#include <hip/hip_runtime.h>
#include <hip/hip_fp16.h>

#define NN 50000
#define NE 200000
#define IND 512
#define HIDD 2000
#define LATD 128

#define M_PAD 50048    // 391*128 = 782*64
#define N1_PAD 2048    // HIDD padded (pad cols forced to exact 0)
#define MT1 391
#define SLAB1 49       // ceil(391/8) M-tiles per XCD
#define NBLK 196       // ceil(NN/256)

typedef _Float16 f16x8 __attribute__((ext_vector_type(8)));
typedef float f32x4 __attribute__((ext_vector_type(4)));

__device__ __forceinline__ void gload_lds16(const _Float16* g, _Float16* l) {
    __builtin_amdgcn_global_load_lds(
        (const __attribute__((address_space(1))) unsigned int*)g,
        (__attribute__((address_space(3))) unsigned int*)l,
        16, 0, 0);
}

// ---- in-degree (int): deg[col[e]] += 1 ----
__global__ void k_degree(const int* __restrict__ col, int* __restrict__ deg) {
    int e = blockIdx.x * 256 + threadIdx.x;
    if (e < NE) atomicAdd(&deg[col[e]], 1);
}

// ---- dis = rsqrt(deg + 1 self-loop) ----
__global__ void k_dis(const int* __restrict__ deg, float* __restrict__ dis) {
    int i = blockIdx.x * 256 + threadIdx.x;
    if (i < NN) dis[i] = rsqrtf((float)deg[i] + 1.0f);
}

// ---- hierarchical exclusive scan: (1) per-block sums ----
__global__ void k_bsum(const int* __restrict__ deg, int* __restrict__ bsum) {
    __shared__ int sm[4];
    int i = blockIdx.x * 256 + threadIdx.x;
    int v = (i < NN) ? deg[i] : 0;
    #pragma unroll
    for (int off = 32; off; off >>= 1) v += __shfl_down(v, off, 64);
    if ((threadIdx.x & 63) == 0) sm[threadIdx.x >> 6] = v;
    __syncthreads();
    if (threadIdx.x == 0) bsum[blockIdx.x] = sm[0] + sm[1] + sm[2] + sm[3];
}

// ---- (2) exclusive scan of the 196 block sums (one block) ----
__global__ void k_bscan(int* __restrict__ bsum) {
    __shared__ int sm[256];
    int tid = threadIdx.x;
    int v = (tid < NBLK) ? bsum[tid] : 0;
    sm[tid] = v;
    __syncthreads();
    #pragma unroll
    for (int off = 1; off < 256; off <<= 1) {
        int t = (tid >= off) ? sm[tid - off] : 0;
        __syncthreads();
        sm[tid] += t;
        __syncthreads();
    }
    if (tid < NBLK) bsum[tid] = sm[tid] - v;   // exclusive
}

// ---- (3) per-block exclusive scan + offset -> row_ptr ----
__global__ void k_scan_final(const int* __restrict__ deg, const int* __restrict__ bsum,
                             int* __restrict__ row_ptr) {
    __shared__ int sm[256];
    int b = blockIdx.x, tid = threadIdx.x;
    int i = b * 256 + tid;
    int v = (i < NN) ? deg[i] : 0;
    sm[tid] = v;
    __syncthreads();
    #pragma unroll
    for (int off = 1; off < 256; off <<= 1) {
        int t = (tid >= off) ? sm[tid - off] : 0;
        __syncthreads();
        sm[tid] += t;
        __syncthreads();
    }
    if (i < NN) row_ptr[i] = bsum[b] + sm[tid] - v;
    if (i == NN - 1) row_ptr[NN] = bsum[b] + sm[tid];
}

// ---- fill CSR: csr_src[row_ptr[c] + cursor[c]++] = r ----
__global__ void k_fill(const int* __restrict__ ei, const int* __restrict__ row_ptr,
                       int* __restrict__ cursor, int* __restrict__ csr_src) {
    int e = blockIdx.x * 256 + threadIdx.x;
    if (e < NE) {
        int r = ei[e], c = ei[NE + e];
        int pos = atomicAdd(&cursor[c], 1);
        csr_src[row_ptr[c] + pos] = r;
    }
}

// ---- LDS-tiled transpose+convert: in f32 [R][C] -> out fp16, out[c*ldo + r] ----
__global__ void k_transpose_tiled(const float* __restrict__ in,
                                  _Float16* __restrict__ out, int R, int C, int ldo) {
    __shared__ float sm[32][33];
    int c0 = blockIdx.x * 32, r0 = blockIdx.y * 32;
    int tx = threadIdx.x & 31, ty = threadIdx.x >> 5;   // 32 x 8
    #pragma unroll
    for (int i = 0; i < 4; ++i) {
        int r = r0 + ty + i * 8, c = c0 + tx;
        sm[ty + i * 8][tx] = (r < R && c < C) ? in[(size_t)r * C + c] : 0.f;
    }
    __syncthreads();
    #pragma unroll
    for (int i = 0; i < 4; ++i) {
        int c = c0 + ty + i * 8, r = r0 + tx;
        if (c < C && r < R) out[(size_t)c * ldo + r] = (_Float16)sm[tx][ty + i * 8];
    }
}

// ---- x f32 -> xh fp16 (8 elems/thread) ----
__global__ void k_xcvt(const float* __restrict__ in, _Float16* __restrict__ out, int n8) {
    int i = blockIdx.x * 256 + threadIdx.x;
    if (i < n8) {
        float4 a = ((const float4*)in)[i * 2];
        float4 b = ((const float4*)in)[i * 2 + 1];
        f16x8 o;
        o[0] = (_Float16)a.x; o[1] = (_Float16)a.y; o[2] = (_Float16)a.z; o[3] = (_Float16)a.w;
        o[4] = (_Float16)b.x; o[5] = (_Float16)b.y; o[6] = (_Float16)b.z; o[7] = (_Float16)b.w;
        ((f16x8*)out)[i] = o;
    }
}

// ---- gather-aggregate x (fp16 src): Ah[dst] = fp16(dd*(sum dis[s]*xh[s] + dd*xh[dst])) ----
__global__ void k_gather_x(const _Float16* __restrict__ xh, const int* __restrict__ row_ptr,
                           const int* __restrict__ csr_src, const float* __restrict__ dis,
                           _Float16* __restrict__ Ah) {
    int dst = blockIdx.x * 4 + (threadIdx.x >> 6);
    if (dst >= NN) return;
    int lane = threadIdx.x & 63;
    float dd = dis[dst];
    f16x8 sv = *(const f16x8*)(xh + (size_t)dst * IND + lane * 8);
    float acc[8];
    #pragma unroll
    for (int i = 0; i < 8; ++i) acc[i] = dd * (float)sv[i];
    int beg = row_ptr[dst], end = row_ptr[dst + 1];
    for (int i = beg; i < end; ++i) {
        int s = csr_src[i];
        float ns = dis[s];
        f16x8 v = *(const f16x8*)(xh + (size_t)s * IND + lane * 8);
        #pragma unroll
        for (int q = 0; q < 8; ++q) acc[q] += ns * (float)v[q];
    }
    f16x8 o;
    #pragma unroll
    for (int i = 0; i < 8; ++i) o[i] = (_Float16)(dd * acc[i]);
    *(f16x8*)(Ah + (size_t)dst * IND + lane * 8) = o;
}

// ---- gather-aggregate t + bias + sigmoid -> out (f32) ----
__global__ void k_gather_t(const float* __restrict__ t, const int* __restrict__ row_ptr,
                           const int* __restrict__ csr_src, const float* __restrict__ dis,
                           const float* __restrict__ b2, float* __restrict__ out) {
    int dst = blockIdx.x * 4 + (threadIdx.x >> 6);
    if (dst >= NN) return;
    int lane = threadIdx.x & 63;
    float dd = dis[dst];
    float2 td = *(const float2*)(t + (size_t)dst * LATD + lane * 2);
    float accx = dd * td.x, accy = dd * td.y;
    int beg = row_ptr[dst], end = row_ptr[dst + 1];
    for (int i = beg; i < end; ++i) {
        int s = csr_src[i];
        float ns = dis[s];
        float2 ts = *(const float2*)(t + (size_t)s * LATD + lane * 2);
        accx += ns * ts.x; accy += ns * ts.y;
    }
    float2 bb = *(const float2*)(b2 + lane * 2);
    float vx = dd * accx + bb.x;
    float vy = dd * accy + bb.y;
    float2 o;
    o.x = 1.0f / (1.0f + __expf(-vx));
    o.y = 1.0f / (1.0f + __expf(-vy));
    *(float2*)(out + (size_t)dst * LATD + lane * 2) = o;
}

// ---- GEMM1: h = relu(Ah @ W1T^T + b1), 128x128 tile, BK=64 (2x32 slices), XCD swizzle ----
__global__ __launch_bounds__(256, 2) void k_gemm1(
    const _Float16* __restrict__ A,    // [M_PAD][512]
    const _Float16* __restrict__ Bt,   // [2048][512]
    const float* __restrict__ bias,    // [2048] (pad zeros)
    _Float16* __restrict__ Ch)         // [M_PAD][2048]
{
    const int b = blockIdx.x;
    const int mT = (b & 7) * SLAB1 + ((b >> 3) >> 4);
    const int nT = (b >> 3) & 15;
    if (mT >= MT1) return;
    const int mBase = mT * 128;
    const int nBase = nT * 128;

    __shared__ __align__(16) _Float16 As[2 * 128 * 32];   // 16 KB: [slice][128][32]
    __shared__ __align__(16) _Float16 Bs[2 * 128 * 32];

    const int tid = threadIdx.x;
    const int lane = tid & 63;
    const int w = tid >> 6;

    const int srow = w * 32 + (lane >> 2);   // + (0|16) per chunk
    const int scol = (lane & 3) * 8;
    const _Float16* Ag0 = A + (size_t)(mBase + srow) * IND + scol;
    const _Float16* Ag1 = Ag0 + (size_t)16 * IND;
    const _Float16* Bg0 = Bt + (size_t)(nBase + srow) * IND + scol;
    const _Float16* Bg1 = Bg0 + (size_t)16 * IND;

    const int wm = (w >> 1) * 64;
    const int wn = (w & 1) * 64;
    const int lm = lane & 15;
    const int quad = lane >> 4;

    f32x4 acc[4][4];
    #pragma unroll
    for (int i = 0; i < 4; ++i)
        #pragma unroll
        for (int j = 0; j < 4; ++j)
            acc[i][j] = (f32x4){0.f, 0.f, 0.f, 0.f};

    for (int k0 = 0; k0 < IND; k0 += 64) {
        #pragma unroll
        for (int s = 0; s < 2; ++s) {
            gload_lds16(Ag0 + k0 + s * 32, As + s * 4096 + w * 1024);
            gload_lds16(Ag1 + k0 + s * 32, As + s * 4096 + w * 1024 + 512);
            gload_lds16(Bg0 + k0 + s * 32, Bs + s * 4096 + w * 1024);
            gload_lds16(Bg1 + k0 + s * 32, Bs + s * 4096 + w * 1024 + 512);
        }
        __syncthreads();

        #pragma unroll
        for (int s = 0; s < 2; ++s) {
            f16x8 af[4], bfr[4];
            #pragma unroll
            for (int mi = 0; mi < 4; ++mi)
                af[mi] = *(const f16x8*)&As[s * 4096 + (wm + mi * 16 + lm) * 32 + quad * 8];
            #pragma unroll
            for (int ni = 0; ni < 4; ++ni)
                bfr[ni] = *(const f16x8*)&Bs[s * 4096 + (wn + ni * 16 + lm) * 32 + quad * 8];
            #pragma unroll
            for (int mi = 0; mi < 4; ++mi)
                #pragma unroll
                for (int ni = 0; ni < 4; ++ni)
                    acc[mi][ni] = __builtin_amdgcn_mfma_f32_16x16x32_f16(
                        af[mi], bfr[ni], acc[mi][ni], 0, 0, 0);
        }
        __syncthreads();
    }

    #pragma unroll
    for (int mi = 0; mi < 4; ++mi) {
        #pragma unroll
        for (int ni = 0; ni < 4; ++ni) {
            int col = nBase + wn + ni * 16 + lm;
            float bval = bias[col];
            #pragma unroll
            for (int r = 0; r < 4; ++r) {
                int rowg = mBase + wm + mi * 16 + quad * 4 + r;
                float v = fmaxf(acc[mi][ni][r] + bval, 0.f);
                Ch[(size_t)rowg * N1_PAD + col] = (_Float16)v;
            }
        }
    }
}

// ---- GEMM2: t = h @ W2T^T, 64x128 tile, BK=64 (2x32 slices), f32 out ----
__global__ __launch_bounds__(256, 2) void k_gemm2(
    const _Float16* __restrict__ A,    // [M_PAD][2048]
    const _Float16* __restrict__ Bt,   // [128][2048]
    float* __restrict__ Cf)            // [M_PAD][128]
{
    __shared__ __align__(16) _Float16 As[2 * 64 * 32];    //  8 KB
    __shared__ __align__(16) _Float16 Bs[2 * 128 * 32];   // 16 KB

    const int tid = threadIdx.x;
    const int lane = tid & 63;
    const int w = tid >> 6;
    const int mBase = blockIdx.x * 64;

    const int srA = w * 16 + (lane >> 2);
    const int srB = w * 32 + (lane >> 2);
    const int scol = (lane & 3) * 8;
    const _Float16* Ag  = A + (size_t)(mBase + srA) * N1_PAD + scol;
    const _Float16* Bg0 = Bt + (size_t)srB * N1_PAD + scol;
    const _Float16* Bg1 = Bg0 + (size_t)16 * N1_PAD;

    const int wm = (w & 1) * 32;
    const int wn = (w >> 1) * 64;
    const int lm = lane & 15;
    const int quad = lane >> 4;

    f32x4 acc[2][4];
    #pragma unroll
    for (int i = 0; i < 2; ++i)
        #pragma unroll
        for (int j = 0; j < 4; ++j)
            acc[i][j] = (f32x4){0.f, 0.f, 0.f, 0.f};

    for (int k0 = 0; k0 < N1_PAD; k0 += 64) {
        #pragma unroll
        for (int s = 0; s < 2; ++s) {
            gload_lds16(Ag + k0 + s * 32, As + s * 2048 + w * 512);
            gload_lds16(Bg0 + k0 + s * 32, Bs + s * 4096 + w * 1024);
            gload_lds16(Bg1 + k0 + s * 32, Bs + s * 4096 + w * 1024 + 512);
        }
        __syncthreads();

        #pragma unroll
        for (int s = 0; s < 2; ++s) {
            f16x8 af[2], bfr[4];
            #pragma unroll
            for (int mi = 0; mi < 2; ++mi)
                af[mi] = *(const f16x8*)&As[s * 2048 + (wm + mi * 16 + lm) * 32 + quad * 8];
            #pragma unroll
            for (int ni = 0; ni < 4; ++ni)
                bfr[ni] = *(const f16x8*)&Bs[s * 4096 + (wn + ni * 16 + lm) * 32 + quad * 8];
            #pragma unroll
            for (int mi = 0; mi < 2; ++mi)
                #pragma unroll
                for (int ni = 0; ni < 4; ++ni)
                    acc[mi][ni] = __builtin_amdgcn_mfma_f32_16x16x32_f16(
                        af[mi], bfr[ni], acc[mi][ni], 0, 0, 0);
        }
        __syncthreads();
    }

    #pragma unroll
    for (int mi = 0; mi < 2; ++mi) {
        #pragma unroll
        for (int ni = 0; ni < 4; ++ni) {
            int col = wn + ni * 16 + lm;
            #pragma unroll
            for (int r = 0; r < 4; ++r) {
                int rowg = mBase + wm + mi * 16 + quad * 4 + r;
                Cf[(size_t)rowg * LATD + col] = acc[mi][ni][r];
            }
        }
    }
}

extern "C" void kernel_launch(void* const* d_in, const int* in_sizes, int n_in,
                              void* d_out, int out_size, void* d_ws, size_t ws_size,
                              hipStream_t stream) {
    const float* x  = (const float*)d_in[0];
    const int* ei   = (const int*)d_in[1];
    const float* W1 = (const float*)d_in[2];
    const float* b1 = (const float*)d_in[3];
    const float* W2 = (const float*)d_in[4];
    const float* b2 = (const float*)d_in[5];
    float* out = (float*)d_out;

    char* p = (char*)d_ws;
    auto alloc = [&](size_t bytes) {
        char* q = p; p += (bytes + 255) & ~(size_t)255; return q;
    };
    int* deg        = (int*)alloc((size_t)NN * 4);
    int* bsum       = (int*)alloc((size_t)NBLK * 4);
    int* row_ptr    = (int*)alloc((size_t)(NN + 1) * 4);
    int* cursor     = (int*)alloc((size_t)NN * 4);
    int* csr_src    = (int*)alloc((size_t)NE * 4);
    float* dis      = (float*)alloc((size_t)NN * 4);
    float* b1pad    = (float*)alloc((size_t)N1_PAD * 4);
    _Float16* W1T   = (_Float16*)alloc((size_t)N1_PAD * IND * 2);   // [2048][512]
    _Float16* W2T   = (_Float16*)alloc((size_t)LATD * N1_PAD * 2);  // [128][2048]
    _Float16* xh    = (_Float16*)alloc((size_t)NN * IND * 2);
    _Float16* Ah    = (_Float16*)alloc((size_t)M_PAD * IND * 2);
    _Float16* h     = (_Float16*)alloc((size_t)M_PAD * N1_PAD * 2);
    float* t        = (float*)alloc((size_t)M_PAD * LATD * 4);

    hipMemsetAsync(deg,    0, (size_t)NN * 4, stream);
    hipMemsetAsync(cursor, 0, (size_t)NN * 4, stream);
    hipMemsetAsync(b1pad,  0, (size_t)N1_PAD * 4, stream);
    hipMemsetAsync(W1T,    0, (size_t)N1_PAD * IND * 2, stream);
    hipMemsetAsync(W2T,    0, (size_t)LATD * N1_PAD * 2, stream);
    hipMemcpyAsync(b1pad, b1, (size_t)HIDD * 4, hipMemcpyDeviceToDevice, stream);

    k_degree<<<(NE + 255) / 256, 256, 0, stream>>>(ei + NE, deg);
    k_dis<<<(NN + 255) / 256, 256, 0, stream>>>(deg, dis);
    k_bsum<<<NBLK, 256, 0, stream>>>(deg, bsum);
    k_bscan<<<1, 256, 0, stream>>>(bsum);
    k_scan_final<<<NBLK, 256, 0, stream>>>(deg, bsum, row_ptr);
    k_fill<<<(NE + 255) / 256, 256, 0, stream>>>(ei, row_ptr, cursor, csr_src);

    {
        dim3 gt1((HIDD + 31) / 32, (IND + 31) / 32);
        k_transpose_tiled<<<gt1, 256, 0, stream>>>(W1, W1T, IND, HIDD, IND);
        dim3 gt2((LATD + 31) / 32, (HIDD + 31) / 32);
        k_transpose_tiled<<<gt2, 256, 0, stream>>>(W2, W2T, HIDD, LATD, N1_PAD);
        k_xcvt<<<(NN * IND / 8 + 255) / 256, 256, 0, stream>>>(x, xh, NN * IND / 8);
    }

    k_gather_x<<<(NN + 3) / 4, 256, 0, stream>>>(xh, row_ptr, csr_src, dis, Ah);

    k_gemm1<<<8 * SLAB1 * 16, 256, 0, stream>>>(Ah, W1T, b1pad, h);
    k_gemm2<<<M_PAD / 64, 256, 0, stream>>>(h, W2T, t);

    k_gather_t<<<(NN + 3) / 4, 256, 0, stream>>>(t, row_ptr, csr_src, dis, b2, out);
}